// Round 7
// baseline (863.770 us; speedup 1.0000x reference)
//
#include <hip/hip_runtime.h>
#include <stdint.h>

// Problem constants
#define N_ROWS 8192
#define D_DIM  1024
#define M_CENT 20000
#define M_PAD  20224          // 79 * 256
#define M_TILES 79            // 256-wide center tiles
#define Y_DIM  256
#define BM 64                 // rows of X per block (2 blocks/CU geometry)
#define BN 256                // centers per M-iteration (wave tile 64x64)
#define BK 64                 // K-chunk of D
#define NCHUNK 16             // D_DIM / BK
#define MSPLIT 8
#define TILES_PER_SPLIT 10    // ceil(79/8)
#define LDSP_STRIDE 264       // 256 + 8 pad: 33 16B-slots/row == 1 mod 8 -> conflict-free

// LDS layout (u16 element offsets into lds_all):
//   buf0: [0, 20480)        = X[64][64] (4096) + Z[256][64] (16384)
//   buf1: [20480, 40960)    = same, second stage buffer
//   p   : [20480, 37376)    = P[64][264] (16896) -- aliases buf1 head
//   norms (R9): [37376, 38016) = xsq f32[64] + zsq f32[256] -- aliases buf1
//               TAIL GAP (p end 37376 .. buf1 end 40960): dead during
//               Phases 2-3 (last reader = chunk-15 MFMAs, pre-barrier);
//               re-staged every tile in Phase 2.
//   buf0 stays free during Phases 2-3 so next-tile chunk-0 prefetch flies.
// Total 40960 elem = 81920 B = EXACTLY half of 160KB -> 2 blocks/CU
// (R7/R8 HW-verified: LDS_Block_Size=81920, Occupancy 22% = 2 blocks/CU).
#define BUFE 20480            // elements per stage buffer
#define ZOFF 4096             // Z offset within a buffer
#define POFF 20480            // p region start (== buf1)
#define XGOFF 37376           // xsq gap region (64 f32 = 128 elem)
#define ZGOFF 37504           // zsq gap region (256 f32 = 512 elem) ends 38016

typedef __attribute__((ext_vector_type(4))) float  f32x4;
typedef __attribute__((ext_vector_type(8))) __bf16 bf16x8;

__device__ __forceinline__ unsigned short f2bf(float f) {
    union { float f; unsigned u; } v; v.f = f;
    unsigned u = v.u;
    u += 0x7FFFu + ((u >> 16) & 1u);   // RNE
    return (unsigned short)(u >> 16);
}

// async global->LDS, 16B per lane. LDS dest must be wave-uniform base + lane*16.
__device__ __forceinline__ void gll16(void* lds, const void* g) {
    __builtin_amdgcn_global_load_lds(
        (const __attribute__((address_space(1))) void*)g,
        (__attribute__((address_space(3))) void*)lds, 16, 0, 0);
}

// cast fp32 rows -> bf16, compute fp32 row sum-of-squares; pad rows -> zeros
__global__ void cast_rows_kernel(const float* __restrict__ src,
                                 unsigned short* __restrict__ dst,
                                 float* __restrict__ sq, int nrows_valid) {
    int row = blockIdx.x;
    int t = threadIdx.x;  // 256 threads, 4 floats each = 1024 = D_DIM
    float s = 0.f;
    if (row < nrows_valid) {
        float4 v = ((const float4*)(src + (size_t)row * D_DIM))[t];
        s = v.x * v.x + v.y * v.y + v.z * v.z + v.w * v.w;
        ushort4 o;
        o.x = f2bf(v.x); o.y = f2bf(v.y); o.z = f2bf(v.z); o.w = f2bf(v.w);
        ((ushort4*)(dst + (size_t)row * D_DIM))[t] = o;
    } else {
        ((ushort4*)(dst + (size_t)row * D_DIM))[t] = make_ushort4(0, 0, 0, 0);
    }
    __shared__ float red[4];
    for (int off = 32; off; off >>= 1) s += __shfl_down(s, off, 64);
    if ((t & 63) == 0) red[t >> 6] = s;
    __syncthreads();
    if (t == 0) sq[row] = red[0] + red[1] + red[2] + red[3];
}

// W [M][Y] fp32 -> WT [Y][M_PAD] bf16, pad rows (centers >= M_CENT) -> 0
__global__ void cast_wT_kernel(const float* __restrict__ w,
                               unsigned short* __restrict__ wT) {
    __shared__ float tile[32][33];
    int k0 = blockIdx.x * 32;   // center dim
    int y0 = blockIdx.y * 32;   // Y dim
    int tx = threadIdx.x & 31;
    int ty = threadIdx.x >> 5;  // 0..7
    #pragma unroll
    for (int i = 0; i < 4; ++i) {
        int k = k0 + ty + i * 8;
        float v = (k < M_CENT) ? w[(size_t)k * Y_DIM + y0 + tx] : 0.f;
        tile[tx][ty + i * 8] = v;     // tile[y_local][k_local]
    }
    __syncthreads();
    #pragma unroll
    for (int i = 0; i < 4; ++i) {
        int yl = ty + i * 8;
        wT[(size_t)(y0 + yl) * M_PAD + k0 + tx] = f2bf(tile[yl][tx]);
    }
}

// ---------------------------------------------------------------------------
// R9 = R8 with ONE change (R8 post-mortem: WRITE 275MB = 75 ideal + ~200MB
// spill; 200MB/(1024blk x 10tiles x 256thr) = 20 dwords = exactly xq[16]+
// zq[4] -> Phase-2 norm registers spill because S(64)+Oacc(64) leave no VGPR
// headroom at the 128-arch file):
//  - Norms EVICTED FROM VGPRs TO LDS, using the buf1 TAIL GAP [37376,38016)
//    (p ends 37376, buf1 ends 40960; tail is dead during Phases 2-3).
//    Per tile: 2 scalar loads/thread (tX: t<64, tZ) issued at TILE TOP --
//    older than CHUNK(0)'s stage, so the existing vmcnt(10) sweeps them
//    (zero added stalls); only 2 VGPRs live across Phase 1 (R6 HW-proved 4
//    is spill-free).  After phase-1->2 barrier: ds_write to gap, one extra
//    lgkmcnt(0)+barrier, Phase 2 reads LDS scalars (R2's proven pattern).
//  - Everything else byte-identical to R8 (clean A/B):
//    * R2 geometry: BM=64, 4 waves, MSPLIT=8, 1024 blocks, 2 resident/CU.
//    * Counted-vmcnt raw-barrier pipeline (T3+T4, HW-verified):
//        barA -> STAGE(next buf, 10 gll16) -> s_waitcnt vmcnt(10) -> barB
//        -> ds_read frags -> 32 MFMA; vmcnt never drains to 0 in phase 1;
//      chunk-15 stages next tile's chunk-0 into buf0 (lands in Phases 2-3).
//    * v_sqrt_f32 inline; launch_bounds(256,2).
//  Sentinels: WRITE ~75MB / FETCH ~450MB = spill dead (primary).
//  Forks: WRITE ~275 -> spill is S/Oacc-structural; WRITE low but dur >=580
//  -> spill wasn't critical-path, ablate phases next.
// ---------------------------------------------------------------------------

#define STAGE(PAR, M0, KBASE) do {                                            \
    _Pragma("unroll")                                                         \
    for (int i_ = 0; i_ < 2; ++i_) {          /* X: 512 16B-chunks */         \
        int lin_ = t + i_ * 256;                                              \
        int row_ = lin_ >> 3, c_ = lin_ & 7;                                  \
        gll16(&lds_all[(PAR) * BUFE + lin_ * 8],                              \
              Xb + (size_t)(row0 + row_) * D_DIM + (KBASE) +                  \
                  ((c_ ^ (row_ & 7)) * 8));                                   \
    }                                                                         \
    _Pragma("unroll")                                                         \
    for (int i_ = 0; i_ < 8; ++i_) {          /* Z: 2048 16B-chunks */        \
        int lin_ = t + i_ * 256;                                              \
        int row_ = lin_ >> 3, c_ = lin_ & 7;                                  \
        gll16(&lds_all[(PAR) * BUFE + ZOFF + lin_ * 8],                       \
              Zb + (size_t)((M0) + row_) * D_DIM + (KBASE) +                  \
                  ((c_ ^ (row_ & 7)) * 8));                                   \
    } } while (0)

// One K-chunk.  PAR literal 0/1.  On entry: [stage(kc)x10] outstanding
// (issued one chunk earlier); buf[PAR^1]'s readers all passed barA.
// vmcnt(10) keeps the 10 JUST-ISSUED ops outstanding and drains everything
// older (stage(kc) + tile-top norm loads) -- robust counting (in-order
// retirement: outstanding<=10 => all older ops retired).
#define CHUNK(PAR, M0N, KBN) do {                                             \
    asm volatile("" ::: "memory");                                            \
    __builtin_amdgcn_s_barrier();          /* barA: buf[PAR^1] free */        \
    asm volatile("" ::: "memory");                                            \
    STAGE(PAR ^ 1, M0N, KBN);                                                 \
    __builtin_amdgcn_sched_barrier(0);                                        \
    asm volatile("s_waitcnt vmcnt(10)" ::: "memory"); /* stage(kc) done */    \
    __builtin_amdgcn_s_barrier();          /* barB: everyone's stage done */  \
    asm volatile("" ::: "memory");                                            \
    _Pragma("unroll")                                                         \
    for (int kt_ = 0; kt_ < 2; ++kt_) {                                       \
        const int sw_ = ((kt_ * 4 + quad) ^ cx) * 8;                          \
        bf16x8 a_[4], b_[4];                                                  \
        _Pragma("unroll")                                                     \
        for (int it_ = 0; it_ < 4; ++it_)                                     \
            a_[it_] = *(const bf16x8*)&lds_all[(PAR) * BUFE +                 \
                (it_ * 16 + l16) * BK + sw_];                                 \
        _Pragma("unroll")                                                     \
        for (int jt_ = 0; jt_ < 4; ++jt_)                                     \
            b_[jt_] = *(const bf16x8*)&lds_all[(PAR) * BUFE + ZOFF +          \
                (wave * 64 + jt_ * 16 + l16) * BK + sw_];                     \
        __builtin_amdgcn_s_setprio(1);                                        \
        _Pragma("unroll")                                                     \
        for (int it_ = 0; it_ < 4; ++it_)                                     \
            _Pragma("unroll")                                                 \
            for (int jt_ = 0; jt_ < 4; ++jt_)                                 \
                S[it_ * 4 + jt_] = __builtin_amdgcn_mfma_f32_16x16x32_bf16(   \
                    a_[it_], b_[jt_], S[it_ * 4 + jt_], 0, 0, 0);             \
        __builtin_amdgcn_s_setprio(0);                                        \
    } } while (0)

__global__ void __launch_bounds__(256, 2)
fused_kernel(const unsigned short* __restrict__ Xb,
             const unsigned short* __restrict__ Zb,
             const unsigned short* __restrict__ WbT,
             const float* __restrict__ xsq,
             const float* __restrict__ zsq,
             const int* __restrict__ bwp,
             float* __restrict__ out) {
    __shared__ unsigned short lds_all[2 * BUFE];   // EXACTLY 81920 B
    float* xg = (float*)&lds_all[XGOFF];           // gap-resident xsq[64]
    float* zg = (float*)&lds_all[ZGOFF];           // gap-resident zsq[256]

    const int t    = threadIdx.x;
    const int wave = t >> 6;      // 0..3: m-slab (phase1 B, phase3 y-slab)
    const int lane = t & 63;
    const int quad = lane >> 4;
    const int l16  = lane & 15;
    const int cx   = l16 & 7;     // row&7 of every frag row this lane touches

    const int row0 = blockIdx.x * BM;          // R2 known-good mapping
    const int mt0  = blockIdx.y * TILES_PER_SPLIT;
    int mt_end = mt0 + TILES_PER_SPLIT;
    if (mt_end > M_TILES) mt_end = M_TILES;

    // bandwidth: int32 per harness convention (Python int 10); tolerate float bits too
    int bwi = *bwp;
    float bw;
    if (bwi > 0 && bwi < 1000000) bw = (float)bwi;
    else { union { int i; float f; } u; u.i = bwi; bw = u.f; }
    const float inv_bw = 1.0f / bw;

    const f32x4 vzero = {0.f, 0.f, 0.f, 0.f};
    f32x4 Oacc[16];
    #pragma unroll
    for (int i = 0; i < 16; ++i) Oacc[i] = vzero;

    // prologue: stage (tile mt0, chunk 0) -> buf0
    STAGE(0, mt0 * BN, 0);
    __builtin_amdgcn_sched_barrier(0);

    for (int mt = mt0; mt < mt_end; ++mt) {
        const int m0 = mt * BN;
        // last tile of split prefetches itself (valid mem, unused)
        const int m0next = (mt + 1 < mt_end) ? m0 + BN : m0;

        // norm loads at TILE TOP: only 2 VGPRs live across Phase 1; issued
        // older than CHUNK(0)'s stage so vmcnt(10) sweeps their completion.
        float tX = 0.f;
        if (t < BM) tX = xsq[row0 + t];
        float tZ = zsq[m0 + t];               // BN == blockDim.x == 256
        __builtin_amdgcn_sched_barrier(0);    // pin issue before the k-loop

        f32x4 S[16];
        #pragma unroll
        for (int i = 0; i < 16; ++i) S[i] = vzero;

        // -------- Phase 1: S[64x256] = X * Z^T over D, counted-vmcnt pipe --
        // chunk kc reads buf[kc&1]; stages kc+1 into buf[(kc+1)&1].
        // kc=15 stages NEXT TILE's chunk 0 into buf0 (disjoint from p/gap),
        // landing during Phases 2-3 -> no drain at tile boundary.
        #pragma unroll 1
        for (int kc = 0; kc < NCHUNK; kc += 2) {
            const bool last = (kc + 2 == NCHUNK);
            CHUNK(0, m0, (kc + 1) * BK);
            CHUNK(1, last ? m0next : m0, last ? 0 : (kc + 2) * BK);
        }

        // phase1 -> phase2: all buf1 readers done before p/gap overwrite it
        asm volatile("" ::: "memory");
        __builtin_amdgcn_s_barrier();
        asm volatile("" ::: "memory");

        // stage norms into the buf1 tail gap (dead until next phase-1)
        if (t < BM) xg[t] = tX;
        zg[t] = tZ;
        asm volatile("s_waitcnt lgkmcnt(0)" ::: "memory");
        __builtin_amdgcn_s_barrier();
        asm volatile("" ::: "memory");

        // -------- Phase 2: P = exp(-sqrt(d2)/bw) -> p (bf16) --------
        // norms read as LDS scalars (quad-broadcast / consecutive-bank;
        // R2's proven pattern).  No norm VGPR arrays -> no spill.
        #pragma unroll
        for (int it = 0; it < 4; ++it) {
            #pragma unroll
            for (int jt = 0; jt < 4; ++jt) {
                f32x4 s4 = S[it * 4 + jt];
                const int col = wave * 64 + jt * 16 + l16;
                const float zq = zg[col];
                #pragma unroll
                for (int r = 0; r < 4; ++r) {
                    const int row = it * 16 + quad * 4 + r;   // C-layout
                    float d2 = xg[row] + zq - 2.0f * s4[r];
                    d2 = fmaxf(d2, 0.f);
                    float d;
                    asm("v_sqrt_f32 %0, %1" : "=v"(d) : "v"(d2));
                    float p = __expf(-d * inv_bw);
                    lds_all[POFF + row * LDSP_STRIDE + col] = f2bf(p);
                }
            }
        }
        // P-write -> P-read: LDS-only drain; buf0 prefetch stays in flight
        asm volatile("s_waitcnt lgkmcnt(0)" ::: "memory");
        __builtin_amdgcn_s_barrier();
        asm volatile("" ::: "memory");

        // -------- Phase 3: O += P[64x256] * Wtile[256x256] --------
        #pragma unroll
        for (int ks = 0; ks < 8; ++ks) {
            const int koff = ks * 32 + quad * 8;
            bf16x8 a[4], b[4];
            #pragma unroll
            for (int rt = 0; rt < 4; ++rt)
                a[rt] = *(const bf16x8*)&lds_all[POFF +
                    (rt * 16 + l16) * LDSP_STRIDE + koff];
            #pragma unroll
            for (int ct = 0; ct < 4; ++ct) {
                const int y = wave * 64 + ct * 16 + l16;
                b[ct] = *(const bf16x8*)(WbT + (size_t)y * M_PAD + m0 + koff);
            }
            __builtin_amdgcn_s_setprio(1);
            #pragma unroll
            for (int rt = 0; rt < 4; ++rt)
                #pragma unroll
                for (int ct = 0; ct < 4; ++ct)
                    Oacc[rt * 4 + ct] = __builtin_amdgcn_mfma_f32_16x16x32_bf16(
                        a[rt], b[ct], Oacc[rt * 4 + ct], 0, 0, 0);
            __builtin_amdgcn_s_setprio(0);
        }
        // next tile's CHUNK(0) barA separates these p reads from the next
        // stage writes into buf1 (p ds_reads are lgkm-drained pre-MFMA).
    }

    // drain the dangling last-tile prefetch before LDS is released
    asm volatile("s_waitcnt vmcnt(0)" ::: "memory");

    // -------- epilogue: accumulate M-splits via device-scope fp32 atomics ----
    #pragma unroll
    for (int rt = 0; rt < 4; ++rt) {
        #pragma unroll
        for (int ct = 0; ct < 4; ++ct) {
            f32x4 v = Oacc[rt * 4 + ct];
            const int y = wave * 64 + ct * 16 + l16;
            #pragma unroll
            for (int r = 0; r < 4; ++r) {
                const int row = row0 + rt * 16 + quad * 4 + r;
                atomicAdd(&out[(size_t)row * Y_DIM + y], v[r]);
            }
        }
    }
}

extern "C" void kernel_launch(void* const* d_in, const int* in_sizes, int n_in,
                              void* d_out, int out_size, void* d_ws, size_t ws_size,
                              hipStream_t stream) {
    const float* X = (const float*)d_in[0];
    const float* Z = (const float*)d_in[1];
    const float* W = (const float*)d_in[2];
    const int*  bw = (const int*)d_in[3];
    float* out = (float*)d_out;

    char* ws = (char*)d_ws;
    size_t off = 0;
    unsigned short* Xb  = (unsigned short*)(ws + off); off += (size_t)N_ROWS * D_DIM * 2;
    unsigned short* Zb  = (unsigned short*)(ws + off); off += (size_t)M_PAD * D_DIM * 2;
    unsigned short* WbT = (unsigned short*)(ws + off); off += (size_t)Y_DIM * M_PAD * 2;
    float* xsq = (float*)(ws + off); off += (size_t)N_ROWS * 4;
    float* zsq = (float*)(ws + off); off += (size_t)M_PAD * 4;
    // total ws use: ~68.7 MB

    hipMemsetAsync(d_out, 0, (size_t)out_size * sizeof(float), stream);
    cast_rows_kernel<<<N_ROWS, 256, 0, stream>>>(X, Xb, xsq, N_ROWS);
    cast_rows_kernel<<<M_PAD, 256, 0, stream>>>(Z, Zb, zsq, M_CENT);
    cast_wT_kernel<<<dim3(M_PAD / 32, Y_DIM / 32), 256, 0, stream>>>(W, WbT);
    fused_kernel<<<dim3(N_ROWS / BM, MSPLIT), 256, 0, stream>>>(
        Xb, Zb, WbT, xsq, zsq, bw, out);
}